// Round 8
// baseline (59.385 us; speedup 1.0000x reference)
//
#include <hip/hip_runtime.h>
#include <cstdint>

#define B_ROWS 4096
#define N_ROWS 8192
#define D_DIM  256
#define TGRID  64                  // 8192 / 128 tiles
#define NJ     4                   // j-tiles per block
#define NBLOCKS 544                // sum_i ceil((64-i)/4)
#define BK     32                  // K-step
#define NKT    8                   // 256 / 32

typedef __attribute__((ext_vector_type(4))) float f32x4;
typedef __attribute__((ext_vector_type(8))) short bf16x8;
typedef __attribute__((ext_vector_type(4))) unsigned short u16x4;

__device__ __forceinline__ unsigned short f2bf(float f) {
    union { float f; unsigned u; } v; v.f = f;
    unsigned r = v.u + 0x7FFF + ((v.u >> 16) & 1);   // RNE
    return (unsigned short)(r >> 16);
}
__device__ __forceinline__ float bf2f(unsigned short h) {
    union { unsigned u; float f; } v; v.u = ((unsigned)h) << 16;
    return v.f;
}

__device__ __forceinline__ void gload16(const void* g, void* l) {
    __builtin_amdgcn_global_load_lds(
        (const __attribute__((address_space(1))) void*)g,
        (__attribute__((address_space(3))) void*)l, 16, 0, 0);
}

__device__ __forceinline__ f32x4 exp4(f32x4 v) {
    f32x4 r;
    r.x = __expf(v.x); r.y = __expf(v.y); r.z = __expf(v.z); r.w = __expf(v.w);
    return r;
}

// ------------- Kernel A: normalize both pair rows + pos dot, one pass -------------
__global__ __launch_bounds__(256) void normpos_kernel(const float* __restrict__ zi,
                                                      const float* __restrict__ zj,
                                                      unsigned short* __restrict__ zn,
                                                      float* __restrict__ pospartial) {
    int wid = threadIdx.x >> 6;
    int lane = threadIdx.x & 63;
    int p = blockIdx.x * 4 + wid;          // 0..B_ROWS-1
    f32x4 ga = *(const f32x4*)(zi + (size_t)p * D_DIM + lane * 4);
    f32x4 gb = *(const f32x4*)(zj + (size_t)p * D_DIM + lane * 4);
    float sa = ga.x * ga.x + ga.y * ga.y + ga.z * ga.z + ga.w * ga.w;
    float sb = gb.x * gb.x + gb.y * gb.y + gb.z * gb.z + gb.w * gb.w;
    #pragma unroll
    for (int m = 1; m < 64; m <<= 1) { sa += __shfl_xor(sa, m, 64); sb += __shfl_xor(sb, m, 64); }
    float fa = 1.41421356237309515f / fmaxf(sqrtf(sa), 1e-8f);
    float fb = 1.41421356237309515f / fmaxf(sqrtf(sb), 1e-8f);
    u16x4 oa, ob;
    oa.x = f2bf(ga.x * fa); oa.y = f2bf(ga.y * fa); oa.z = f2bf(ga.z * fa); oa.w = f2bf(ga.w * fa);
    ob.x = f2bf(gb.x * fb); ob.y = f2bf(gb.y * fb); ob.z = f2bf(gb.z * fb); ob.w = f2bf(gb.w * fb);
    *(u16x4*)(zn + (size_t)p * D_DIM + lane * 4) = oa;
    *(u16x4*)(zn + (size_t)(p + B_ROWS) * D_DIM + lane * 4) = ob;
    float d = bf2f(oa.x) * bf2f(ob.x) + bf2f(oa.y) * bf2f(ob.y)
            + bf2f(oa.z) * bf2f(ob.z) + bf2f(oa.w) * bf2f(ob.w);
    #pragma unroll
    for (int m = 1; m < 64; m <<= 1) d += __shfl_xor(d, m, 64);
    if (lane == 0) pospartial[p] = d;
}

// ------------- Kernel C: A-in-registers GEMM, 4 j-tiles per block -------------
// Block: i-tile (128 rows) x up-to-4 j-tiles (128 cols each). 4 waves 2x2, wave-tile
// 64x64 (acc 4x4). A-panel (128x256) staged to LDS once, reg-loaded (af[4][8], static),
// LDS region then reused as B 3-buffer rotation (8KB each). Per K-step: 2 gloads (B),
// 4 ds_reads (B-frags), 16 MFMA, counted vmcnt(2), raw s_barrier. Swizzle (row>>1)&3.
__global__ __launch_bounds__(256, 2) void simclr_gemm_kernel(const unsigned short* __restrict__ zn,
                                                             float* __restrict__ P) {
    __shared__ unsigned short SH[33792];        // 64KB A-panel / B-rot + 2KB partials
    float* rPpart = (float*)&SH[32768];         // [2][128]
    float* cPpart = rPpart + 256;               // [2][128]

    const int tid = threadIdx.x;
    const int lane = tid & 63, wid = tid >> 6;
    const int wr = wid >> 1, wc = wid & 1;      // 2x2 wave grid

    // XCD-bijective swizzle (544 % 8 == 0); same-i blocks adjacent -> share A panel in L2
    int bid = (int)((blockIdx.x & 7) * (NBLOCKS / 8) + (blockIdx.x >> 3));
    // decode bid -> (ti, jc): per i, ceil((64-i)/4) chunks of j-tiles
    int ti = 0, cum = 0;
    for (;;) {
        int c = (TGRID - ti + 3) >> 2;
        if (bid < cum + c) break;
        cum += c; ++ti;
    }
    const int jc = bid - cum;
    const int j0 = ti + 4 * jc;
    const int nj = min(NJ, TGRID - j0);
    const int G = nj * NKT;

    const char* gA = (const char*)zn + (size_t)ti * 128 * 512;   // row stride 512 B

    // staging geometry (8KB slice = 128 rows x 64B): thread -> rows {tid>>2, 64+tid>>2},
    // 16B chunk tid&3; source chunk pre-swizzled sch = (tid&3) ^ ((tid>>3)&3) = slot^((row>>1)&3).
    const int r0 = tid >> 2;
    const int sch = (tid & 3) ^ ((tid >> 3) & 3);
    const size_t gbase = (size_t)r0 * 512 + (size_t)sch * 16;
    const unsigned lo0 = (unsigned)tid * 8;          // ushort idx (byte tid*16)
    const unsigned lo1 = 2048u + (unsigned)tid * 8;  // row 64 = ushort 2048

    // ---- prologue: stage full A panel (8 slices), reg-load, then free region for B ----
    #pragma unroll
    for (int s = 0; s < 8; ++s) {
        gload16(gA + gbase + s * 64,            &SH[s * 4096 + lo0]);
        gload16(gA + gbase + 64 * 512 + s * 64, &SH[s * 4096 + lo1]);
    }
    asm volatile("s_waitcnt vmcnt(0)" ::: "memory");
    __builtin_amdgcn_sched_barrier(0);
    __builtin_amdgcn_s_barrier();
    __builtin_amdgcn_sched_barrier(0);

    // frag addressing: row r -> k-chunk kc = (lane>>4) ^ ((r>>1)&3), r bases x16
    const int kc = (lane >> 4) ^ (((lane & 15) >> 1) & 3);
    const int arow = wr * 64 + (lane & 15);
    const int brow = wc * 64 + (lane & 15);

    bf16x8 af[4][8];                            // 128 VGPR, all-static indices
    #pragma unroll
    for (int kt = 0; kt < 8; ++kt)
        #pragma unroll
        for (int m = 0; m < 4; ++m)
            af[m][kt] = *(const bf16x8*)&SH[kt * 4096 + (arow + m * 16) * 32 + kc * 8];
    asm volatile("s_waitcnt lgkmcnt(0)" ::: "memory");
    __builtin_amdgcn_sched_barrier(0);
    __builtin_amdgcn_s_barrier();               // all waves done with A region
    __builtin_amdgcn_sched_barrier(0);

#define STAGE_B(h_) do {                                                       \
    int jt_ = (h_) >> 3, kt_ = (h_) & 7, b_ = (h_) % 3;                        \
    const char* gBp = (const char*)zn + (size_t)(j0 + jt_) * 128 * 512;        \
    gload16(gBp + gbase + kt_ * 64,            &SH[b_ * 4096 + lo0]);          \
    gload16(gBp + gbase + 64 * 512 + kt_ * 64, &SH[b_ * 4096 + lo1]);          \
} while (0)

    STAGE_B(0);
    STAGE_B(1);

    f32x4 acc[4][4];
    #pragma unroll
    for (int m = 0; m < 4; ++m)
        #pragma unroll
        for (int n = 0; n < 4; ++n)
            acc[m][n] = (f32x4){0.f, 0.f, 0.f, 0.f};

    for (int jt = 0; jt < nj; ++jt) {
        const int tj = j0 + jt;
        #pragma unroll
        for (int kt = 0; kt < 8; ++kt) {        // kt STATIC (af index)
            const int g = jt * 8 + kt;
            if (g == G - 1) asm volatile("s_waitcnt vmcnt(0)" ::: "memory");
            else            asm volatile("s_waitcnt vmcnt(2)" ::: "memory");
            __builtin_amdgcn_sched_barrier(0);
            __builtin_amdgcn_s_barrier();
            __builtin_amdgcn_sched_barrier(0);

            const int b = (2 * jt + kt) % 3;    // == g % 3
            bf16x8 bfr[4];
            #pragma unroll
            for (int n = 0; n < 4; ++n)
                bfr[n] = *(const bf16x8*)&SH[b * 4096 + (brow + n * 16) * 32 + kc * 8];

            __builtin_amdgcn_s_setprio(1);
            #pragma unroll
            for (int m = 0; m < 4; ++m)
                #pragma unroll
                for (int n = 0; n < 4; ++n)
                    acc[m][n] = __builtin_amdgcn_mfma_f32_16x16x32_bf16(af[m][kt], bfr[n], acc[m][n], 0, 0, 0);
            __builtin_amdgcn_s_setprio(0);

            __builtin_amdgcn_sched_barrier(0);  // keep stage below the reads of buf b
            if (g + 2 < G) STAGE_B(g + 2);
        }

        // ---- epilogue for tile (ti, tj): raw barriers only (keep B prefetch in flight) ----
        float cs[4] = {0.f, 0.f, 0.f, 0.f};
        #pragma unroll
        for (int m = 0; m < 4; ++m) {
            f32x4 ef[4];
            #pragma unroll
            for (int n = 0; n < 4; ++n) ef[n] = exp4(acc[m][n]);
            #pragma unroll
            for (int n = 0; n < 4; ++n)
                acc[m][n] = (f32x4){0.f, 0.f, 0.f, 0.f};   // re-zero for next jt
            f32x4 rv = ef[0] + ef[1] + ef[2] + ef[3];
            #pragma unroll
            for (int msk = 1; msk <= 8; msk <<= 1) {
                rv.x += __shfl_xor(rv.x, msk, 64);
                rv.y += __shfl_xor(rv.y, msk, 64);
                rv.z += __shfl_xor(rv.z, msk, 64);
                rv.w += __shfl_xor(rv.w, msk, 64);
            }
            if ((lane & 15) == 0) {
                int rbase = wr * 64 + m * 16 + (lane >> 4) * 4;
                rPpart[wc * 128 + rbase + 0] = rv.x;
                rPpart[wc * 128 + rbase + 1] = rv.y;
                rPpart[wc * 128 + rbase + 2] = rv.z;
                rPpart[wc * 128 + rbase + 3] = rv.w;
            }
            #pragma unroll
            for (int n = 0; n < 4; ++n)
                cs[n] += ef[n].x + ef[n].y + ef[n].z + ef[n].w;
        }
        #pragma unroll
        for (int n = 0; n < 4; ++n) {
            float c = cs[n];
            c += __shfl_xor(c, 16, 64);
            c += __shfl_xor(c, 32, 64);
            if (lane < 16) cPpart[wr * 128 + wc * 64 + n * 16 + lane] = c;
        }
        asm volatile("s_waitcnt lgkmcnt(0)" ::: "memory");
        __builtin_amdgcn_sched_barrier(0);
        __builtin_amdgcn_s_barrier();
        __builtin_amdgcn_sched_barrier(0);

        if (tid < 128) {
            // row-sums of i-panel: slot tj, segment ti (each (ti,tj) has unique writer)
            P[(size_t)tj * N_ROWS + (size_t)ti * 128 + tid] = rPpart[tid] + rPpart[128 + tid];
        } else if (tj != ti) {
            int t = tid - 128;
            // col-sums -> rows of j-panel: slot ti, segment tj (ti<tj only)
            P[(size_t)ti * N_ROWS + (size_t)tj * 128 + t] = cPpart[t] + cPpart[128 + t];
        }
        // next jt's first barrier (kt=0) orders rP/cP reuse
    }
#undef STAGE_B
}

// ------------- Kernel E: per-row reduce over 64 slots + log (+fold pos) -------------
__global__ __launch_bounds__(256) void reduce_rows_kernel(const float* __restrict__ P,
                                                          const float* __restrict__ pospartial,
                                                          float* __restrict__ blockpart) {
    const float E2 = 7.38905609893065f;   // exp(self-sim) = e^2
    int row = blockIdx.x * 256 + threadIdx.x;
    float s = 0.f;
    #pragma unroll 16
    for (int src = 0; src < TGRID; ++src)
        s += P[(size_t)src * N_ROWS + row];
    float v = logf(s - E2);
    if (threadIdx.x < 128)
        v -= 2.0f * pospartial[blockIdx.x * 128 + threadIdx.x];
    #pragma unroll
    for (int m = 1; m < 64; m <<= 1) v += __shfl_xor(v, m, 64);
    __shared__ float ws[4];
    if ((threadIdx.x & 63) == 0) ws[threadIdx.x >> 6] = v;
    __syncthreads();
    if (threadIdx.x == 0) blockpart[blockIdx.x] = ws[0] + ws[1] + ws[2] + ws[3];
}

// ------------- Kernel F: out = sum(blockpart) / N -------------
__global__ __launch_bounds__(64) void final_kernel(const float* __restrict__ blockpart,
                                                   float* __restrict__ out) {
    int lane = threadIdx.x;
    float v = (lane < 32) ? blockpart[lane] : 0.f;
    #pragma unroll
    for (int m = 1; m < 64; m <<= 1) v += __shfl_xor(v, m, 64);
    if (lane == 0) out[0] = v / (float)N_ROWS;
}

extern "C" void kernel_launch(void* const* d_in, const int* in_sizes, int n_in,
                              void* d_out, int out_size, void* d_ws, size_t ws_size,
                              hipStream_t stream) {
    const float* zi = (const float*)d_in[0];
    const float* zj = (const float*)d_in[1];
    char* ws = (char*)d_ws;
    unsigned short* zn = (unsigned short*)ws;                        // 4 MB
    float* P = (float*)(ws + 4 * 1024 * 1024);                       // 2 MB (64 x 8192 f32)
    float* pospartial = (float*)(ws + 6 * 1024 * 1024);              // 16 KB
    float* blockpart = (float*)(ws + 6 * 1024 * 1024 + 16 * 1024);   // 128 B

    normpos_kernel<<<B_ROWS / 4, 256, 0, stream>>>(zi, zj, zn, pospartial);
    simclr_gemm_kernel<<<NBLOCKS, 256, 0, stream>>>(zn, P);
    reduce_rows_kernel<<<N_ROWS / 256, 256, 0, stream>>>(P, pospartial, blockpart);
    final_kernel<<<1, 64, 0, stream>>>(blockpart, (float*)d_out);
}

// Round 9
// 45.286 us; speedup vs baseline: 1.3113x; 1.3113x over previous
//
#include <hip/hip_runtime.h>
#include <cstdint>

#define B_ROWS 4096
#define N_ROWS 8192
#define D_DIM  256
#define BT     128                 // block tile 128x128
#define TGRID  64                  // 8192 / 128
#define NTILES 2080                // TGRID*(TGRID+1)/2
#define BK     32                  // K-step
#define NKT    8                   // 256 / 32

typedef __attribute__((ext_vector_type(4))) float f32x4;
typedef __attribute__((ext_vector_type(8))) short bf16x8;
typedef __attribute__((ext_vector_type(4))) unsigned short u16x4;

__device__ __forceinline__ unsigned short f2bf(float f) {
    union { float f; unsigned u; } v; v.f = f;
    unsigned r = v.u + 0x7FFF + ((v.u >> 16) & 1);   // RNE
    return (unsigned short)(r >> 16);
}
__device__ __forceinline__ float bf2f(unsigned short h) {
    union { unsigned u; float f; } v; v.u = ((unsigned)h) << 16;
    return v.f;
}

__device__ __forceinline__ void gload16(const void* g, void* l) {
    __builtin_amdgcn_global_load_lds(
        (const __attribute__((address_space(1))) void*)g,
        (__attribute__((address_space(3))) void*)l, 16, 0, 0);
}

__device__ __forceinline__ f32x4 exp4(f32x4 v) {
    f32x4 r;
    r.x = __expf(v.x); r.y = __expf(v.y); r.z = __expf(v.z); r.w = __expf(v.w);
    return r;
}

// ------------- Kernel A: normalize both pair rows + pos dot, one pass -------------
__global__ __launch_bounds__(256) void normpos_kernel(const float* __restrict__ zi,
                                                      const float* __restrict__ zj,
                                                      unsigned short* __restrict__ zn,
                                                      float* __restrict__ pospartial) {
    int wid = threadIdx.x >> 6;
    int lane = threadIdx.x & 63;
    int p = blockIdx.x * 4 + wid;          // 0..B_ROWS-1
    f32x4 ga = *(const f32x4*)(zi + (size_t)p * D_DIM + lane * 4);
    f32x4 gb = *(const f32x4*)(zj + (size_t)p * D_DIM + lane * 4);
    float sa = ga.x * ga.x + ga.y * ga.y + ga.z * ga.z + ga.w * ga.w;
    float sb = gb.x * gb.x + gb.y * gb.y + gb.z * gb.z + gb.w * gb.w;
    #pragma unroll
    for (int m = 1; m < 64; m <<= 1) { sa += __shfl_xor(sa, m, 64); sb += __shfl_xor(sb, m, 64); }
    float fa = 1.41421356237309515f / fmaxf(sqrtf(sa), 1e-8f);
    float fb = 1.41421356237309515f / fmaxf(sqrtf(sb), 1e-8f);
    u16x4 oa, ob;
    oa.x = f2bf(ga.x * fa); oa.y = f2bf(ga.y * fa); oa.z = f2bf(ga.z * fa); oa.w = f2bf(ga.w * fa);
    ob.x = f2bf(gb.x * fb); ob.y = f2bf(gb.y * fb); ob.z = f2bf(gb.z * fb); ob.w = f2bf(gb.w * fb);
    *(u16x4*)(zn + (size_t)p * D_DIM + lane * 4) = oa;
    *(u16x4*)(zn + (size_t)(p + B_ROWS) * D_DIM + lane * 4) = ob;
    float d = bf2f(oa.x) * bf2f(ob.x) + bf2f(oa.y) * bf2f(ob.y)
            + bf2f(oa.z) * bf2f(ob.z) + bf2f(oa.w) * bf2f(ob.w);
    #pragma unroll
    for (int m = 1; m < 64; m <<= 1) d += __shfl_xor(d, m, 64);
    if (lane == 0) pospartial[p] = d;
}

// ------------- Kernel C: upper-tri 128x128 GEMM + exp + partial row/col sums -------------
// m97-discipline: 256 thr = 4 waves (2x2), wave-tile 64x64 (acc 4x4), BK=32,
// SINGLE LDS buffer, plain __syncthreads, compiler-scheduled loop body.
// Swizzle: chunk ^= (row>>1)&3 on both stage-source and read (verified 0-conflict).
__global__ __launch_bounds__(256, 3) void simclr_gemm_kernel(const unsigned short* __restrict__ zn,
                                                             float* __restrict__ P) {
    __shared__ unsigned short As[BT * BK];   // 8 KB
    __shared__ unsigned short Bs[BT * BK];   // 8 KB
    __shared__ float rPpart[2][BT];          // per-wc row partials
    __shared__ float cPpart[2][BT];          // per-wr col partials

    const int tid = threadIdx.x;
    const int lane = tid & 63, wid = tid >> 6;
    const int wr = wid >> 1, wc = wid & 1;      // 2x2 wave grid

    // XCD-bijective chunked swizzle (2080 % 8 == 0)
    int bid = (int)((blockIdx.x & 7) * (NTILES / 8) + (blockIdx.x >> 3));
    // decode bid -> (ti,tj), ti<=tj, row-major upper triangle (TGRID=64)
    int ti = (int)((129.0f - sqrtf(16641.0f - 8.0f * (float)bid)) * 0.5f);
    while ((ti + 1) * TGRID - ((ti + 1) * ti) / 2 <= bid) ++ti;
    while (ti * TGRID - (ti * (ti - 1)) / 2 > bid) --ti;
    const int tj = ti + (bid - (ti * TGRID - (ti * (ti - 1)) / 2));

    const char* gA = (const char*)zn + (size_t)ti * BT * 512;   // row stride 512 B
    const char* gB = (const char*)zn + (size_t)tj * BT * 512;

    // staging: per K-step each matrix = 128 rows x 64 B = 8 KB = 2 issues of 4 KB.
    // thread -> (row = tid>>2 [+64], slot = tid&3). LDS byte off = tid*16 [+4096].
    // global chunk pre-swizzled: sch = slot ^ ((row>>1)&3) = (tid&3) ^ ((tid>>3)&3).
    const int r0 = tid >> 2;
    const int sch = (tid & 3) ^ ((tid >> 3) & 3);
    const size_t gof0 = (size_t)r0 * 512 + (size_t)sch * 16;
    const size_t gof1 = (size_t)(64 + r0) * 512 + (size_t)sch * 16;
    const unsigned lo0 = (unsigned)tid * 8;          // ushort index (byte tid*16)
    const unsigned lo1 = 2048u + (unsigned)tid * 8;  // row 64 = ushort 64*32 = 2048

    f32x4 acc[4][4];
    #pragma unroll
    for (int m = 0; m < 4; ++m)
        #pragma unroll
        for (int n = 0; n < 4; ++n)
            acc[m][n] = (f32x4){0.f, 0.f, 0.f, 0.f};

    // frag read: row r -> lds k-chunk kc = (lane>>4) ^ ((r>>1)&3); frag row bases x16
    const int kc = (lane >> 4) ^ (((lane & 15) >> 1) & 3);
    const int arow = wr * 64 + (lane & 15);
    const int brow = wc * 64 + (lane & 15);

    #pragma unroll
    for (int kt = 0; kt < NKT; ++kt) {
        const size_t kb = (size_t)kt * 64;
        gload16(gA + gof0 + kb, &As[lo0]);
        gload16(gA + gof1 + kb, &As[lo1]);
        gload16(gB + gof0 + kb, &Bs[lo0]);
        gload16(gB + gof1 + kb, &Bs[lo1]);
        __syncthreads();            // drains vmcnt -> staged data visible

        bf16x8 af[4], bfr[4];
        #pragma unroll
        for (int m = 0; m < 4; ++m)
            af[m] = *(const bf16x8*)&As[(arow + m * 16) * 32 + kc * 8];
        #pragma unroll
        for (int n = 0; n < 4; ++n)
            bfr[n] = *(const bf16x8*)&Bs[(brow + n * 16) * 32 + kc * 8];

        #pragma unroll
        for (int m = 0; m < 4; ++m)
            #pragma unroll
            for (int n = 0; n < 4; ++n)
                acc[m][n] = __builtin_amdgcn_mfma_f32_16x16x32_bf16(af[m], bfr[n], acc[m][n], 0, 0, 0);
        __syncthreads();            // all reads done before next stage overwrites
    }

    // ---- epilogue: exp; unique-writer LDS partials (no atomics) ----
    float cs[4] = {0.f, 0.f, 0.f, 0.f};
    #pragma unroll
    for (int m = 0; m < 4; ++m) {
        f32x4 ef[4];
        #pragma unroll
        for (int n = 0; n < 4; ++n) ef[n] = exp4(acc[m][n]);
        f32x4 rv = ef[0] + ef[1] + ef[2] + ef[3];
        #pragma unroll
        for (int msk = 1; msk <= 8; msk <<= 1) {
            rv.x += __shfl_xor(rv.x, msk, 64);
            rv.y += __shfl_xor(rv.y, msk, 64);
            rv.z += __shfl_xor(rv.z, msk, 64);
            rv.w += __shfl_xor(rv.w, msk, 64);
        }
        if ((lane & 15) == 0) {
            int rbase = wr * 64 + m * 16 + (lane >> 4) * 4;
            rPpart[wc][rbase + 0] = rv.x;
            rPpart[wc][rbase + 1] = rv.y;
            rPpart[wc][rbase + 2] = rv.z;
            rPpart[wc][rbase + 3] = rv.w;
        }
        #pragma unroll
        for (int n = 0; n < 4; ++n)
            cs[n] += ef[n].x + ef[n].y + ef[n].z + ef[n].w;
    }
    #pragma unroll
    for (int n = 0; n < 4; ++n) {
        float c = cs[n];
        c += __shfl_xor(c, 16, 64);
        c += __shfl_xor(c, 32, 64);
        if (lane < 16) cPpart[wr][wc * 64 + n * 16 + lane] = c;
    }
    __syncthreads();

    if (tid < BT) {
        P[(size_t)tj * N_ROWS + ti * BT + tid] = rPpart[0][tid] + rPpart[1][tid];
    } else if (ti != tj) {
        int t = tid - BT;
        P[(size_t)ti * N_ROWS + tj * BT + t] = cPpart[0][t] + cPpart[1][t];
    }
}

// ------------- Kernel E: per-row reduce over 64 slots + log (+fold pos) -------------
__global__ __launch_bounds__(256) void reduce_rows_kernel(const float* __restrict__ P,
                                                          const float* __restrict__ pospartial,
                                                          float* __restrict__ blockpart) {
    const float E2 = 7.38905609893065f;   // exp(self-sim) = e^2
    int row = blockIdx.x * 256 + threadIdx.x;
    float s = 0.f;
    #pragma unroll 16
    for (int src = 0; src < TGRID; ++src)
        s += P[(size_t)src * N_ROWS + row];
    float v = logf(s - E2);
    if (threadIdx.x < 128)
        v -= 2.0f * pospartial[blockIdx.x * 128 + threadIdx.x];
    #pragma unroll
    for (int m = 1; m < 64; m <<= 1) v += __shfl_xor(v, m, 64);
    __shared__ float ws[4];
    if ((threadIdx.x & 63) == 0) ws[threadIdx.x >> 6] = v;
    __syncthreads();
    if (threadIdx.x == 0) blockpart[blockIdx.x] = ws[0] + ws[1] + ws[2] + ws[3];
}

// ------------- Kernel F: out = sum(blockpart) / N -------------
__global__ __launch_bounds__(64) void final_kernel(const float* __restrict__ blockpart,
                                                   float* __restrict__ out) {
    int lane = threadIdx.x;
    float v = (lane < 32) ? blockpart[lane] : 0.f;
    #pragma unroll
    for (int m = 1; m < 64; m <<= 1) v += __shfl_xor(v, m, 64);
    if (lane == 0) out[0] = v / (float)N_ROWS;
}

extern "C" void kernel_launch(void* const* d_in, const int* in_sizes, int n_in,
                              void* d_out, int out_size, void* d_ws, size_t ws_size,
                              hipStream_t stream) {
    const float* zi = (const float*)d_in[0];
    const float* zj = (const float*)d_in[1];
    char* ws = (char*)d_ws;
    unsigned short* zn = (unsigned short*)ws;                        // 4 MB
    float* P = (float*)(ws + 4 * 1024 * 1024);                       // 2 MB (64 x 8192 f32)
    float* pospartial = (float*)(ws + 6 * 1024 * 1024);              // 16 KB
    float* blockpart = (float*)(ws + 6 * 1024 * 1024 + 16 * 1024);   // 128 B

    normpos_kernel<<<B_ROWS / 4, 256, 0, stream>>>(zi, zj, zn, pospartial);
    simclr_gemm_kernel<<<NTILES, 256, 0, stream>>>(zn, P);
    reduce_rows_kernel<<<N_ROWS / 256, 256, 0, stream>>>(P, pospartial, blockpart);
    final_kernel<<<1, 64, 0, stream>>>(blockpart, (float*)d_out);
}